// Round 3
// baseline (350.268 us; speedup 1.0000x reference)
//
#include <hip/hip_runtime.h>

// DCTPolicy: coeffs = scatter(mean + exp(log_std)*eps), log_prob, entropy.
//
// R2 structure: split into pure-direction streams.
//  producer: read 151 MB inputs (HBM), compute samples, write 50 MB compact
//            (param order, L3-resident) + per-block partials -> d_ws.
//  writer:   read compact samples (L3), stage in LDS (stride-17), write the
//            201 MB canvas exactly once with nontemporal float4 stores.
//  reduce:   12288 partials -> log_prob, entropy.
// flat_idx input unused (zigzag map is arithmetic, rank table below).

constexpr int W = 4096;
constexpr int H = 4096;
constexpr long long CHW = 3LL * 4096 * 4096;           // 50331648
constexpr long long NPAR = 12582912;                   // C*NH*NW*K
constexpr float LOG2PI = 1.8378770664093453f;          // ln(2*pi)
constexpr int NBLK = 12288;
constexpr float NTOT = 12582912.0f;

typedef float f32x4 __attribute__((ext_vector_type(4)));

// RT[u] = ranks for row u of an 8x8 block, byte v = zigzag rank of (u,v),
// 0xFF = not among first 16 zigzag coefficients.
__device__ __constant__ unsigned long long RT[8] = {
    0xFFFFFF0A09030200ull,  // u=0: v0=0 v1=2 v2=3 v3=9 v4=10
    0xFFFFFFFF0B080401ull,  // u=1: v0=1 v1=4 v2=8 v3=11
    0xFFFFFFFFFF0C0705ull,  // u=2: v0=5 v1=7 v2=12
    0xFFFFFFFFFFFF0D06ull,  // u=3: v0=6 v1=13
    0xFFFFFFFFFFFFFF0Eull,  // u=4: v0=14
    0xFFFFFFFFFFFFFF0Full,  // u=5: v0=15
    0xFFFFFFFFFFFFFFFFull,  // u=6: none
    0xFFFFFFFFFFFFFFFFull   // u=7: none
};

// ---- Producer: pure streaming read, compact sample write ----
__global__ __launch_bounds__(256) void producer_kernel(
    const float* __restrict__ mean,
    const float* __restrict__ log_std,
    const float* __restrict__ eps,
    float* __restrict__ smp_out,
    float2* __restrict__ partials)
{
    const int t = threadIdx.x;
    const long long g = (long long)blockIdx.x * 1024 + 4 * t;

    const float4 m4 = *(const float4*)(mean    + g);
    const float4 l4 = *(const float4*)(log_std + g);
    const float4 e4 = *(const float4*)(eps     + g);

    float4 s4;
    s4.x = m4.x + __builtin_expf(l4.x) * e4.x;
    s4.y = m4.y + __builtin_expf(l4.y) * e4.y;
    s4.z = m4.z + __builtin_expf(l4.z) * e4.z;
    s4.w = m4.w + __builtin_expf(l4.w) * e4.w;
    *(float4*)(smp_out + g) = s4;

    float s1 = e4.x * e4.x + e4.y * e4.y + e4.z * e4.z + e4.w * e4.w;
    float s2 = l4.x + l4.y + l4.z + l4.w;
#pragma unroll
    for (int off = 32; off > 0; off >>= 1) {
        s1 += __shfl_xor(s1, off, 64);
        s2 += __shfl_xor(s2, off, 64);
    }
    __shared__ float p1[4], p2[4];
    if ((t & 63) == 0) { p1[t >> 6] = s1; p2[t >> 6] = s2; }
    __syncthreads();
    if (t == 0) {
        partials[blockIdx.x] = make_float2(p1[0] + p1[1] + p1[2] + p1[3],
                                           p2[0] + p2[1] + p2[2] + p2[3]);
    }
}

// ---- Writer: L3-hot sample read, pure nontemporal write of the canvas ----
__global__ __launch_bounds__(256) void writer_kernel(
    const float* __restrict__ smp_in,
    float* __restrict__ out)
{
    __shared__ float smp[64 * 17];

    const int t   = threadIdx.x;
    const int bid = blockIdx.x;
    const int c   = bid >> 12;
    const int rem = bid & 4095;
    const int bh  = rem >> 3;             // tile row 0..511
    const int sx  = rem & 7;              // 512-wide strip 0..7

    const long long pbase = (long long)(c * 512 + bh) * 8192 + (long long)sx * 1024;
    const float4 s4 = *(const float4*)(smp_in + pbase + 4 * t);
    const float sv[4] = {s4.x, s4.y, s4.z, s4.w};
#pragma unroll
    for (int j = 0; j < 4; ++j) {
        const int idx = 4 * t + j;
        smp[(idx >> 4) * 17 + (idx & 15)] = sv[j];
    }
    __syncthreads();

    const long long obase = (long long)c * ((long long)H * W)
                          + (long long)(bh * 8) * W + sx * 512;
#pragma unroll
    for (int q = 0; q < 4; ++q) {
        const int f    = t + 256 * q;        // 0..1023 float4 slots
        const int u    = f >> 7;             // row 0..7 (wave-uniform)
        const int x4   = f & 127;            // float4 col 0..127
        const int tile = x4 >> 1;
        const int vb   = (x4 & 1) * 4;
        const unsigned long long row = RT[u];
        f32x4 o;
#pragma unroll
        for (int j = 0; j < 4; ++j) {
            const unsigned r = (unsigned)((row >> (8 * (vb + j))) & 0xFFull);
            const float v = smp[tile * 17 + (int)(r & 15u)];
            o[j] = (r != 0xFFu) ? v : 0.0f;
        }
        __builtin_nontemporal_store(
            o, (f32x4*)(out + obase + (long long)u * W + x4 * 4));
    }
}

__global__ __launch_bounds__(256) void reduce_kernel(
    const float2* __restrict__ partials,
    float* __restrict__ out)
{
    const int t = threadIdx.x;
    float s1 = 0.f, s2 = 0.f;
    for (int i = t; i < NBLK; i += 256) {
        const float2 v = partials[i];
        s1 += v.x;
        s2 += v.y;
    }
#pragma unroll
    for (int off = 32; off > 0; off >>= 1) {
        s1 += __shfl_xor(s1, off, 64);
        s2 += __shfl_xor(s2, off, 64);
    }
    __shared__ float a1[4], a2[4];
    if ((t & 63) == 0) { a1[t >> 6] = s1; a2[t >> 6] = s2; }
    __syncthreads();
    if (t == 0) {
        const float S1 = a1[0] + a1[1] + a1[2] + a1[3];  // sum eps^2
        const float S2 = a2[0] + a2[1] + a2[2] + a2[3];  // sum log_std
        out[CHW]     = -0.5f * S1 - S2 - 0.5f * NTOT * LOG2PI;
        out[CHW + 1] = 0.5f * (1.0f + LOG2PI) * NTOT + S2;
    }
}

extern "C" void kernel_launch(void* const* d_in, const int* in_sizes, int n_in,
                              void* d_out, int out_size, void* d_ws, size_t ws_size,
                              hipStream_t stream) {
    const float* mean    = (const float*)d_in[0];
    const float* log_std = (const float*)d_in[1];
    const float* eps     = (const float*)d_in[2];
    float* out = (float*)d_out;

    float*  samples  = (float*)d_ws;                       // 50.3 MB
    float2* partials = (float2*)((char*)d_ws + NPAR * 4);  // 96 KiB

    producer_kernel<<<NBLK, 256, 0, stream>>>(mean, log_std, eps, samples, partials);
    writer_kernel<<<NBLK, 256, 0, stream>>>(samples, out);
    reduce_kernel<<<1, 256, 0, stream>>>(partials, out);
}

// Round 4
// 343.274 us; speedup vs baseline: 1.0204x; 1.0204x over previous
//
#include <hip/hip_runtime.h>

// DCTPolicy: coeffs = scatter(mean + exp(log_std)*eps), log_prob, entropy.
//
// R3 structure: back to R1's fused minimum-traffic kernel (151 MB read +
// 201 MB write, no sample round-trip), now with NONTEMPORAL canvas stores
// so the 197 MB write stream doesn't write-allocate in L2/L3 and evict the
// L3-resident inputs (restore-copy leaves them hot). Partials -> d_ws,
// tiny reduce kernel for the two scalars. flat_idx unused (arithmetic map).

constexpr int W = 4096;
constexpr int H = 4096;
constexpr long long CHW = 3LL * 4096 * 4096;           // 50331648
constexpr float LOG2PI = 1.8378770664093453f;          // ln(2*pi)
constexpr int NBLK = 12288;
constexpr float NTOT = 12582912.0f;                    // C*NH*NW*K

typedef float f32x4 __attribute__((ext_vector_type(4)));

// RT[u] = ranks for row u of an 8x8 block, byte v = zigzag rank of (u,v),
// 0xFF = not among first 16 zigzag coefficients.
__device__ __constant__ unsigned long long RT[8] = {
    0xFFFFFF0A09030200ull,  // u=0: v0=0 v1=2 v2=3 v3=9 v4=10
    0xFFFFFFFF0B080401ull,  // u=1: v0=1 v1=4 v2=8 v3=11
    0xFFFFFFFFFF0C0705ull,  // u=2: v0=5 v1=7 v2=12
    0xFFFFFFFFFFFF0D06ull,  // u=3: v0=6 v1=13
    0xFFFFFFFFFFFFFF0Eull,  // u=4: v0=14
    0xFFFFFFFFFFFFFF0Full,  // u=5: v0=15
    0xFFFFFFFFFFFFFFFFull,  // u=6: none
    0xFFFFFFFFFFFFFFFFull   // u=7: none
};

__global__ __launch_bounds__(256) void dct_policy_kernel(
    const float* __restrict__ mean,
    const float* __restrict__ log_std,
    const float* __restrict__ eps,
    float* __restrict__ out,
    float2* __restrict__ partials)
{
    __shared__ float smp[64 * 17];
    __shared__ float p1[4], p2[4];

    const int t   = threadIdx.x;          // 0..255
    const int bid = blockIdx.x;           // 0..12287
    const int c   = bid >> 12;
    const int rem = bid & 4095;
    const int bh  = rem >> 3;             // tile row 0..511
    const int sx  = rem & 7;              // 512-wide strip 0..7

    // ---- Phase 1: load 1024 contiguous params, compute samples into LDS ----
    const long long pbase = (long long)(c * 512 + bh) * 8192 + (long long)sx * 1024;

    const float4 m4 = *(const float4*)(mean    + pbase + 4 * t);
    const float4 l4 = *(const float4*)(log_std + pbase + 4 * t);
    const float4 e4 = *(const float4*)(eps     + pbase + 4 * t);

    const float mv[4] = {m4.x, m4.y, m4.z, m4.w};
    const float lv[4] = {l4.x, l4.y, l4.z, l4.w};
    const float ev[4] = {e4.x, e4.y, e4.z, e4.w};

    float s1 = 0.f, s2 = 0.f;
#pragma unroll
    for (int j = 0; j < 4; ++j) {
        const int idx  = 4 * t + j;
        const int tile = idx >> 4;
        const int rank = idx & 15;
        const float s  = mv[j] + __builtin_expf(lv[j]) * ev[j]; // COEFF_SCALE=1
        smp[tile * 17 + rank] = s;
        s1 += ev[j] * ev[j];
        s2 += lv[j];
    }

#pragma unroll
    for (int off = 32; off > 0; off >>= 1) {
        s1 += __shfl_xor(s1, off, 64);
        s2 += __shfl_xor(s2, off, 64);
    }
    if ((t & 63) == 0) { p1[t >> 6] = s1; p2[t >> 6] = s2; }

    __syncthreads();   // covers both smp[] and p1/p2

    if (t == 0) {
        partials[bid] = make_float2(p1[0] + p1[1] + p1[2] + p1[3],
                                    p2[0] + p2[1] + p2[2] + p2[3]);
    }

    // ---- Phase 2: write 8x512 strip, nontemporal float4, exactly once ----
    const long long obase = (long long)c * ((long long)H * W)
                          + (long long)(bh * 8) * W + sx * 512;
#pragma unroll
    for (int q = 0; q < 4; ++q) {
        const int f    = t + 256 * q;        // 0..1023 float4 slots
        const int u    = f >> 7;             // row 0..7 (wave-uniform)
        const int x4   = f & 127;            // float4 col 0..127
        const int tile = x4 >> 1;
        const int vb   = (x4 & 1) * 4;
        const unsigned long long row = RT[u];
        f32x4 o;
#pragma unroll
        for (int j = 0; j < 4; ++j) {
            const unsigned r = (unsigned)((row >> (8 * (vb + j))) & 0xFFull);
            const float v = smp[tile * 17 + (int)(r & 15u)];
            o[j] = (r != 0xFFu) ? v : 0.0f;
        }
        __builtin_nontemporal_store(
            o, (f32x4*)(out + obase + (long long)u * W + x4 * 4));
    }
}

__global__ __launch_bounds__(256) void reduce_kernel(
    const float2* __restrict__ partials,
    float* __restrict__ out)
{
    const int t = threadIdx.x;
    float s1 = 0.f, s2 = 0.f;
    for (int i = t; i < NBLK; i += 256) {
        const float2 v = partials[i];
        s1 += v.x;
        s2 += v.y;
    }
#pragma unroll
    for (int off = 32; off > 0; off >>= 1) {
        s1 += __shfl_xor(s1, off, 64);
        s2 += __shfl_xor(s2, off, 64);
    }
    __shared__ float a1[4], a2[4];
    if ((t & 63) == 0) { a1[t >> 6] = s1; a2[t >> 6] = s2; }
    __syncthreads();
    if (t == 0) {
        const float S1 = a1[0] + a1[1] + a1[2] + a1[3];  // sum eps^2
        const float S2 = a2[0] + a2[1] + a2[2] + a2[3];  // sum log_std
        out[CHW]     = -0.5f * S1 - S2 - 0.5f * NTOT * LOG2PI;
        out[CHW + 1] = 0.5f * (1.0f + LOG2PI) * NTOT + S2;
    }
}

extern "C" void kernel_launch(void* const* d_in, const int* in_sizes, int n_in,
                              void* d_out, int out_size, void* d_ws, size_t ws_size,
                              hipStream_t stream) {
    const float* mean    = (const float*)d_in[0];
    const float* log_std = (const float*)d_in[1];
    const float* eps     = (const float*)d_in[2];
    float* out = (float*)d_out;
    float2* partials = (float2*)d_ws;   // 12288 * 8 B = 96 KiB

    dct_policy_kernel<<<NBLK, 256, 0, stream>>>(mean, log_std, eps, out, partials);
    reduce_kernel<<<1, 256, 0, stream>>>(partials, out);
}

// Round 6
// 335.518 us; speedup vs baseline: 1.0440x; 1.0231x over previous
//
#include <hip/hip_runtime.h>

// DCTPolicy: coeffs = scatter(mean + exp(log_std)*eps), log_prob, entropy.
//
// R4 structure: fused minimum-traffic kernel (as R1), but 4 strips per block
// (4096 params): all 12 float4 loads per thread issued up front (192 B/lane
// in flight, 4x the MLP of R1), single barrier, then 16 float4 stores.
// Theory: R1's 90 us (vs ~52 us floor) was latency-bound, not BW-bound.
// NT stores reverted (R3 showed neutral/negative). flat_idx unused.
// (R5 resubmit: R4 bench never ran — GPU broker timeout.)

constexpr int W = 4096;
constexpr int H = 4096;
constexpr long long CHW = 3LL * 4096 * 4096;           // 50331648
constexpr float LOG2PI = 1.8378770664093453f;          // ln(2*pi)
constexpr int NBLK = 3072;                             // 4 strips per block
constexpr float NTOT = 12582912.0f;                    // C*NH*NW*K

// RT[u] = ranks for row u of an 8x8 block, byte v = zigzag rank of (u,v),
// 0xFF = not among first 16 zigzag coefficients.
__device__ __constant__ unsigned long long RT[8] = {
    0xFFFFFF0A09030200ull,  // u=0: v0=0 v1=2 v2=3 v3=9 v4=10
    0xFFFFFFFF0B080401ull,  // u=1: v0=1 v1=4 v2=8 v3=11
    0xFFFFFFFFFF0C0705ull,  // u=2: v0=5 v1=7 v2=12
    0xFFFFFFFFFFFF0D06ull,  // u=3: v0=6 v1=13
    0xFFFFFFFFFFFFFF0Eull,  // u=4: v0=14
    0xFFFFFFFFFFFFFF0Full,  // u=5: v0=15
    0xFFFFFFFFFFFFFFFFull,  // u=6: none
    0xFFFFFFFFFFFFFFFFull   // u=7: none
};

__global__ __launch_bounds__(256) void dct_policy_kernel(
    const float* __restrict__ mean,
    const float* __restrict__ log_std,
    const float* __restrict__ eps,
    float* __restrict__ out,
    float2* __restrict__ partials)
{
    __shared__ float smp[4][64 * 17];   // 4 strips, stride-17 pad
    __shared__ float p1[4], p2[4];

    const int t   = threadIdx.x;        // 0..255
    const int bid = blockIdx.x;         // 0..3071
    const int c   = bid >> 10;          // channel (1024 blocks per channel)
    const int rem = bid & 1023;
    const int bh  = rem >> 1;           // tile row 0..511
    const int hx  = rem & 1;            // which 2048-col half

    // ---- Phase 1: 12 independent float4 loads, all in flight ----
    const long long pbase = (long long)(c * 512 + bh) * 8192 + (long long)hx * 4096;

    float4 m4[4], l4[4], e4[4];
#pragma unroll
    for (int k = 0; k < 4; ++k) {
        const long long g = pbase + k * 1024 + 4 * t;
        m4[k] = *(const float4*)(mean    + g);
        l4[k] = *(const float4*)(log_std + g);
        e4[k] = *(const float4*)(eps     + g);
    }

    const int tile = t >> 2;            // (4t+j)>>4 = t>>2 for j=0..3
    const int rb   = (t & 3) * 4;       // base rank within tile
    float s1 = 0.f, s2 = 0.f;
#pragma unroll
    for (int k = 0; k < 4; ++k) {
        const float mv[4] = {m4[k].x, m4[k].y, m4[k].z, m4[k].w};
        const float lv[4] = {l4[k].x, l4[k].y, l4[k].z, l4[k].w};
        const float ev[4] = {e4[k].x, e4[k].y, e4[k].z, e4[k].w};
#pragma unroll
        for (int j = 0; j < 4; ++j) {
            const float s = mv[j] + __builtin_expf(lv[j]) * ev[j]; // SCALE=1
            smp[k][tile * 17 + rb + j] = s;
            s1 += ev[j] * ev[j];
            s2 += lv[j];
        }
    }

#pragma unroll
    for (int off = 32; off > 0; off >>= 1) {
        s1 += __shfl_xor(s1, off, 64);
        s2 += __shfl_xor(s2, off, 64);
    }
    if ((t & 63) == 0) { p1[t >> 6] = s1; p2[t >> 6] = s2; }

    __syncthreads();   // covers smp[] and p1/p2

    if (t == 0) {
        partials[bid] = make_float2(p1[0] + p1[1] + p1[2] + p1[3],
                                    p2[0] + p2[1] + p2[2] + p2[3]);
    }

    // ---- Phase 2: write 8x2048 strip, each output exactly once ----
    const long long obase = (long long)c * ((long long)H * W)
                          + (long long)(bh * 8) * W + (long long)hx * 2048;
#pragma unroll
    for (int k = 0; k < 4; ++k) {
        const long long ob = obase + k * 512;
#pragma unroll
        for (int q = 0; q < 4; ++q) {
            const int f    = t + 256 * q;    // 0..1023 float4 slots
            const int u    = f >> 7;         // row 0..7 (wave-uniform)
            const int x4   = f & 127;        // float4 col 0..127
            const int tl   = x4 >> 1;
            const int vb   = (x4 & 1) * 4;
            const unsigned long long row = RT[u];
            float4 o;
            float* ov = (float*)&o;
#pragma unroll
            for (int j = 0; j < 4; ++j) {
                const unsigned r = (unsigned)((row >> (8 * (vb + j))) & 0xFFull);
                const float v = smp[k][tl * 17 + (int)(r & 15u)];
                ov[j] = (r != 0xFFu) ? v : 0.0f;
            }
            *(float4*)(out + ob + (long long)u * W + x4 * 4) = o;
        }
    }
}

__global__ __launch_bounds__(256) void reduce_kernel(
    const float2* __restrict__ partials,
    float* __restrict__ out)
{
    const int t = threadIdx.x;
    float s1 = 0.f, s2 = 0.f;
    for (int i = t; i < NBLK; i += 256) {
        const float2 v = partials[i];
        s1 += v.x;
        s2 += v.y;
    }
#pragma unroll
    for (int off = 32; off > 0; off >>= 1) {
        s1 += __shfl_xor(s1, off, 64);
        s2 += __shfl_xor(s2, off, 64);
    }
    __shared__ float a1[4], a2[4];
    if ((t & 63) == 0) { a1[t >> 6] = s1; a2[t >> 6] = s2; }
    __syncthreads();
    if (t == 0) {
        const float S1 = a1[0] + a1[1] + a1[2] + a1[3];  // sum eps^2
        const float S2 = a2[0] + a2[1] + a2[2] + a2[3];  // sum log_std
        out[CHW]     = -0.5f * S1 - S2 - 0.5f * NTOT * LOG2PI;
        out[CHW + 1] = 0.5f * (1.0f + LOG2PI) * NTOT + S2;
    }
}

extern "C" void kernel_launch(void* const* d_in, const int* in_sizes, int n_in,
                              void* d_out, int out_size, void* d_ws, size_t ws_size,
                              hipStream_t stream) {
    const float* mean    = (const float*)d_in[0];
    const float* log_std = (const float*)d_in[1];
    const float* eps     = (const float*)d_in[2];
    float* out = (float*)d_out;
    float2* partials = (float2*)d_ws;   // 3072 * 8 B = 24 KiB

    dct_policy_kernel<<<NBLK, 256, 0, stream>>>(mean, log_std, eps, out, partials);
    reduce_kernel<<<1, 256, 0, stream>>>(partials, out);
}